// Round 5
// baseline (254.218 us; speedup 1.0000x reference)
//
#include <hip/hip_runtime.h>

// SpatialAttention fp32: B=128, C=3, H=W=256, 8x8 patches, FEAT=192, ENC=16.
// R5: weights persistent in VGPRs (lane = feature: lane l owns f = l, 64+l,
// 128+l). 4096 single-wave blocks, 32 consecutive patches per wave (p =
// wid*32+it => b,ii fixed per wave, jj=it: L1 reuses the 32B half-lines).
// Patch loop has ZERO weight loads (R4's per-patch s_load storm = the stall).
// Encoder reduce: single-wave LDS transpose, stride 17 (write conflict-free,
// read 2-way = free), double-buffered -> 1 barrier/patch.
// softmax needs no max-subtraction: out = relu(...) bounded ~<=12.

constexpr int NPATCH = 128 * 32 * 32;
constexpr int NWAVES = 4096;
constexpr int PPW    = NPATCH / NWAVES;   // 32 patches per wave
constexpr float L2E  = 1.4426950408889634f;

__global__ __launch_bounds__(64, 3) void spatial_attn(
    const float* __restrict__ x,      // [128][3][256][256]
    const float* __restrict__ Wenc,   // [16][192]
    const float* __restrict__ benc,   // [16]
    const float* __restrict__ Wdec,   // [192][16]
    const float* __restrict__ bdec,   // [192]
    float* __restrict__ y)            // [128][3][256][256]
{
  __shared__ float red[2][64 * 17];
  const int lane = threadIdx.x;           // 0..63
  const int wid  = blockIdx.x;            // 4096 single-wave blocks

  // ---- Persistent weights: loaded once, live in VGPRs for all 32 patches --
  float wenc[3][16];                      // Wenc[e][64c+lane]
  #pragma unroll
  for (int c = 0; c < 3; ++c)
    #pragma unroll
    for (int e = 0; e < 16; ++e)
      wenc[c][e] = Wenc[e * 192 + c * 64 + lane];   // coalesced dword

  float wdec[3][16], bd[3];               // Wdec[64c+lane][0..15]
  #pragma unroll
  for (int c = 0; c < 3; ++c) {
    const float* wr = Wdec + (c * 64 + lane) * 16;
    const float4 a0 = *(const float4*)(wr);
    const float4 a1 = *(const float4*)(wr + 4);
    const float4 a2 = *(const float4*)(wr + 8);
    const float4 a3 = *(const float4*)(wr + 12);
    wdec[c][0]=a0.x;  wdec[c][1]=a0.y;  wdec[c][2]=a0.z;  wdec[c][3]=a0.w;
    wdec[c][4]=a1.x;  wdec[c][5]=a1.y;  wdec[c][6]=a1.z;  wdec[c][7]=a1.w;
    wdec[c][8]=a2.x;  wdec[c][9]=a2.y;  wdec[c][10]=a2.z; wdec[c][11]=a2.w;
    wdec[c][12]=a3.x; wdec[c][13]=a3.y; wdec[c][14]=a3.z; wdec[c][15]=a3.w;
    bd[c] = bdec[c * 64 + lane];
  }
  const int   eI  = lane >> 2, qI = lane & 3;
  const float bev = benc[eI];             // bias for this lane's reduce slot

  // p = wid*32+it  =>  b = wid>>5, ii = wid&31 (fixed), jj = it
  // lane's element: + c*65536 + (lane>>3)*256 + (lane&7)
  const size_t wbase = (size_t)(wid >> 5) * 196608 + (size_t)(wid & 31) * 2048
                     + (size_t)(lane >> 3) * 256 + (size_t)(lane & 7);

  // ---- Software-pipelined x stream: prefetch patch it+1 during it ----
  float xn0 = x[wbase], xn1 = x[wbase + 65536], xn2 = x[wbase + 131072];

  #pragma unroll 1
  for (int it = 0; it < PPW; ++it) {
    const float x0 = xn0, x1 = xn1, x2 = xn2;
    const size_t baseC = wbase + (size_t)it * 8;
    if (it + 1 < PPW) {
      const size_t baseN = baseC + 8;
      xn0 = x[baseN]; xn1 = x[baseN + 65536]; xn2 = x[baseN + 131072];
    }

    // Encoder partials -> LDS transpose buffer (stride 17: conflict-free)
    float* rbuf = red[it & 1];
    #pragma unroll
    for (int e = 0; e < 16; ++e) {
      float a = wenc[0][e] * x0;
      a = fmaf(wenc[1][e], x1, a);
      a = fmaf(wenc[2][e], x2, a);
      rbuf[lane * 17 + e] = a;
    }
    __syncthreads();                      // 1-wave block: cheap

    // Lane (e=lane>>2, q=lane&3) sums its 16-lane chunk, then 2-step shfl
    float r = 0.0f;
    #pragma unroll
    for (int j = 0; j < 16; ++j) r += rbuf[(qI * 16 + j) * 17 + eI];
    r += __shfl_xor(r, 1);
    r += __shfl_xor(r, 2);
    r = fmaxf(r + bev, 0.0f);             // enc[e] at lanes 4e..4e+3

    float enc[16];                        // broadcast -> wave-uniform SGPRs
    #pragma unroll
    for (int e = 0; e < 16; ++e) enc[e] = __shfl(r, 4 * e);

    // Decoder: this lane's 3 outputs, weights already in VGPRs
    float o[3], ex[3], s = 0.0f;
    #pragma unroll
    for (int c = 0; c < 3; ++c) {
      float v = bd[c];
      #pragma unroll
      for (int e = 0; e < 16; ++e) v = fmaf(wdec[c][e], enc[e], v);
      v = fmaxf(v, 0.0f);
      o[c]  = v;
      ex[c] = __builtin_amdgcn_exp2f(v * L2E);
      s += ex[c];
    }
    // Softmax denominator over all 192 features (64 lanes x 3)
    s += __shfl_xor(s, 1);  s += __shfl_xor(s, 2);  s += __shfl_xor(s, 4);
    s += __shfl_xor(s, 8);  s += __shfl_xor(s, 16); s += __shfl_xor(s, 32);
    const float inv = __builtin_amdgcn_rcpf(s);

    #pragma unroll
    for (int c = 0; c < 3; ++c)
      y[baseC + (size_t)c * 65536] = ex[c] * inv * o[c];
  }
}

extern "C" void kernel_launch(void* const* d_in, const int* in_sizes, int n_in,
                              void* d_out, int out_size, void* d_ws, size_t ws_size,
                              hipStream_t stream) {
  const float* x    = (const float*)d_in[0];
  const float* Wenc = (const float*)d_in[1];
  const float* benc = (const float*)d_in[2];
  const float* Wdec = (const float*)d_in[3];
  const float* bdec = (const float*)d_in[4];
  float* y = (float*)d_out;
  dim3 grid(NWAVES), block(64);
  hipLaunchKernelGGL(spatial_attn, grid, block, 0, stream, x, Wenc, benc, Wdec, bdec, y);
}